// Round 6
// baseline (241.794 us; speedup 1.0000x reference)
//
#include <hip/hip_runtime.h>
#include <hip/hip_bf16.h>

typedef __attribute__((ext_vector_type(8))) short bf16x8;
typedef __attribute__((ext_vector_type(4))) float f32x4;

__device__ inline short f2bf(float f) {
    __hip_bfloat16 h = __float2bfloat16(f);
    short s;
    __builtin_memcpy(&s, &h, 2);
    return s;
}
__device__ inline float bf2f(short s) {
    unsigned int u = ((unsigned int)(unsigned short)s) << 16;
    float f;
    __builtin_memcpy(&f, &u, 4);
    return f;
}

// async 16B global->LDS; dest must be wave-uniform base + lane*16
__device__ inline void cp16_async(const void* g, void* l) {
    __builtin_amdgcn_global_load_lds(
        (const __attribute__((address_space(1))) void*)g,
        (__attribute__((address_space(3))) void*)l, 16, 0, 0);
}

// ---------------- prep (round-5, passing) ----------------

__global__ void prep_kernel(const float* __restrict__ x, short* __restrict__ Xp,
                            const float* __restrict__ W0, const float* __restrict__ W1,
                            const float* __restrict__ W2, const float* __restrict__ W3,
                            short* __restrict__ PW, short* __restrict__ WoT) {
    int bid = blockIdx.x;
    if (bid < 4096) {
        int f = bid * 256 + threadIdx.x;           // 0..1,048,575
        int mtf = f >> 13, r = f & 8191, kb = r >> 7, row = r & 127;
        const float* src = x + ((size_t)(mtf * 128 + row) * 512 + kb * 8);
        float4 a = ((const float4*)src)[0];
        float4 bq = ((const float4*)src)[1];
        short t[8];
        t[0] = f2bf(a.x);  t[1] = f2bf(a.y);  t[2] = f2bf(a.z);  t[3] = f2bf(a.w);
        t[4] = f2bf(bq.x); t[5] = f2bf(bq.y); t[6] = f2bf(bq.z); t[7] = f2bf(bq.w);
        ((int4*)Xp)[f] = *(const int4*)t;
    } else if (bid < 4480) {
        int g = (bid - 4096) * 256 + threadIdx.x;  // 0..98303
        int lane = g & 63, ksg = (g >> 6) & 15, nn = g >> 10;
        int w = nn >> 5;
        int nl = (nn & 31) * 16 + (lane & 15);
        int k0 = ksg * 32 + (lane >> 4) * 8;
        const float* W = (w == 0) ? W0 : (w == 1) ? W1 : W2;
        short t[8];
#pragma unroll
        for (int e = 0; e < 8; ++e) t[e] = f2bf(W[(size_t)(k0 + e) * 512 + nl]);
        ((int4*)PW)[g] = *(const int4*)t;
    } else {
        int i = (bid - 4480) * 256 + threadIdx.x;  // 0..262143
        int n = i >> 9, k = i & 511;
        WoT[i] = f2bf(W3[k * 512 + n]);
    }
}

// ---------------- proj_qkv (round-5, passing, unchanged) ----------------

#define KSTEP(ks) { \
    bf16x8 af[4], bfr[4]; \
    _Pragma("unroll") for (int i = 0; i < 4; ++i) \
        af[i] = *(const bf16x8*)&Xs[((ks) * 512 + quad * 128 + wm * 64 + i * 16 + lr) * 8]; \
    _Pragma("unroll") for (int j = 0; j < 4; ++j) \
        bfr[j] = *(const bf16x8*)&PB[((size_t)((j * 16 + (ks)) * 64 + lane)) * 8]; \
    _Pragma("unroll") for (int i = 0; i < 4; ++i) \
        _Pragma("unroll") for (int j = 0; j < 4; ++j) \
            acc[i * 4 + j] = __builtin_amdgcn_mfma_f32_16x16x32_bf16(af[i], bfr[j], acc[i * 4 + j], 0, 0, 0); }

__global__ __launch_bounds__(512, 2) void proj_qkv(const short* __restrict__ Xp,
                                                   const short* __restrict__ PW,
                                                   short* __restrict__ Qb, short* __restrict__ Kb,
                                                   short* __restrict__ Vt, short* __restrict__ Kt) {
    __shared__ __attribute__((aligned(16))) short Xs[65536];
    const int tid = threadIdx.x, lane = tid & 63, wv = tid >> 6;
    const int lr = lane & 15, quad = lane >> 4;
    const int wm = wv >> 2, wn = wv & 3;
    const int bid = blockIdx.x;
    const int swz = (bid & 7) * 32 + (bid >> 3);
    const int mt = swz >> 1, half = swz & 1;
    const short* Ap = Xp + (size_t)mt * 65536;
#pragma unroll
    for (int j = 0; j < 8; ++j) {
        const int f = j * 512 + tid;
        cp16_async(Ap + (size_t)f * 8, (char*)Xs + f * 16);
    }
    __builtin_amdgcn_sched_barrier(0);
#pragma unroll
    for (int j = 8; j < 16; ++j) {
        const int f = j * 512 + tid;
        cp16_async(Ap + (size_t)f * 8, (char*)Xs + f * 16);
    }
    __builtin_amdgcn_sched_barrier(0);
    const int b = mt >> 5;
    const int tl0 = (mt & 31) * 128 + wm * 64;
    const int trow0 = mt * 128 + wm * 64;
    for (int pass = 0; pass < 3; ++pass) {
        const int gc0 = half * 768 + pass * 256;
        f32x4 acc[16];
#pragma unroll
        for (int i = 0; i < 16; ++i) acc[i] = (f32x4){0.f, 0.f, 0.f, 0.f};
        const short* PB = PW + (size_t)((gc0 >> 4) + wn * 4) * 8192;
        if (pass == 0) {
            asm volatile("s_waitcnt vmcnt(8)" ::: "memory");
            __builtin_amdgcn_sched_barrier(0);
            __builtin_amdgcn_s_barrier();
            __builtin_amdgcn_sched_barrier(0);
#pragma unroll 4
            for (int ks = 0; ks < 8; ++ks) KSTEP(ks)
            __builtin_amdgcn_sched_barrier(0);
            asm volatile("s_waitcnt vmcnt(0)" ::: "memory");
            __builtin_amdgcn_sched_barrier(0);
            __builtin_amdgcn_s_barrier();
            __builtin_amdgcn_sched_barrier(0);
#pragma unroll 4
            for (int ks = 8; ks < 16; ++ks) KSTEP(ks)
        } else {
#pragma unroll 4
            for (int ks = 0; ks < 16; ++ks) KSTEP(ks)
        }
        const int p = gc0 >> 9;
        const int fc0 = (gc0 & 511) + wn * 64;
        if (p < 2) {
            short* C = p ? Kb : Qb;
#pragma unroll
            for (int i = 0; i < 4; ++i)
#pragma unroll
                for (int j = 0; j < 4; ++j) {
                    const size_t base = (size_t)(trow0 + i * 16 + quad * 4) * 512 + fc0 + j * 16 + lr;
#pragma unroll
                    for (int r = 0; r < 4; ++r)
                        C[base + (size_t)r * 512] = f2bf(acc[i * 4 + j][r]);
                }
        }
        if (p >= 1) {
            short* T = (p == 1) ? Kt : Vt;
#pragma unroll
            for (int i = 0; i < 4; ++i)
#pragma unroll
                for (int j = 0; j < 4; ++j) {
                    const int f = fc0 + j * 16 + lr;
                    short tmp[4];
#pragma unroll
                    for (int r = 0; r < 4; ++r) tmp[r] = f2bf(acc[i * 4 + j][r]);
                    *(int2*)&T[((size_t)b * 512 + f) * 4096 + tl0 + i * 16 + quad * 4] = *(const int2*)tmp;
                }
        }
    }
}

// ========== generic persist-A core pieces (row-major global, no packing) ==========
// LDS slot for frag (row, X) = row*NF + (X ^ (row&7)); NF = K/8 frags/row (SH = log2 NF).
// Staging walks global contiguously (permuted 16B within each row); ds_read 2-way free.

template <int SH>
__device__ inline void stage_panel(const short* __restrict__ G, int lda_s,
                                   short* lds, int tid) {
    constexpr int NF = 1 << SH;
#pragma unroll
    for (int j = 0; j < NF / 4; ++j) {          // 128*NF/512 slots per thread
        const int s = j * 512 + tid;
        const int row = s >> SH;
        const int X = (s & (NF - 1)) ^ (row & 7);
        cp16_async(G + (size_t)row * lda_s + X * 8, (char*)lds + s * 16);
    }
}

// one K=32 step: A from persistent LDS panel, B streamed 16B/lane from row-major global
template <int SH, int NJ>
__device__ inline void kstep_pg(const short* __restrict__ Apan, int ks,
                                const short* __restrict__ B, int ldb_s, int kb,
                                int mbase, int lr, int quad, f32x4* acc) {
    bf16x8 af[4], bfr[NJ];
#pragma unroll
    for (int i = 0; i < 4; ++i) {
        const int mr = mbase + i * 16 + lr;
        af[i] = *(const bf16x8*)&Apan[((mr << SH) + ((ks * 4 + quad) ^ (mr & 7))) * 8];
    }
#pragma unroll
    for (int j = 0; j < NJ; ++j)
        bfr[j] = *(const bf16x8*)&B[(size_t)(j * 16 + lr) * ldb_s + kb + quad * 8];
#pragma unroll
    for (int i = 0; i < 4; ++i)
#pragma unroll
        for (int j = 0; j < NJ; ++j)
            acc[i * NJ + j] = __builtin_amdgcn_mfma_f32_16x16x32_bf16(af[i], bfr[j], acc[i * NJ + j], 0, 0, 0);
}

#define WAIT_BAR(N) \
    __builtin_amdgcn_sched_barrier(0); \
    asm volatile("s_waitcnt vmcnt(" #N ")" ::: "memory"); \
    __builtin_amdgcn_sched_barrier(0); \
    __builtin_amdgcn_s_barrier(); \
    __builtin_amdgcn_sched_barrier(0);

// ---------------- phaseA: AM[bc][v][k] = sum_t Vt[v][t] Kt[k][t] ----------------
// grid (4 ftile, 1, 64 bc), 512 thr; persist Vt-slice 64KB; stream Kt; 1 barrier.
__global__ __launch_bounds__(512, 2) void phaseA(const short* __restrict__ Vt,
                                                 const short* __restrict__ Kt,
                                                 short* __restrict__ AM) {
    __shared__ __attribute__((aligned(16))) short Apan[32768];
    const int tid = threadIdx.x, lane = tid & 63, wv = tid >> 6;
    const int lr = lane & 15, quad = lane >> 4;
    const int wm = wv >> 2, wn = wv & 3;
    const int ft = blockIdx.x, bc = blockIdx.z, b = bc >> 4, c = bc & 15;
    stage_panel<5>(Vt + ((size_t)(b * 512 + ft * 128)) * 4096 + c * 256, 4096, Apan, tid);
    WAIT_BAR(0)
    const short* Bk = Kt + ((size_t)(b * 512 + wn * 128)) * 4096 + c * 256;
    f32x4 acc[32];
#pragma unroll
    for (int i = 0; i < 32; ++i) acc[i] = (f32x4){0.f, 0.f, 0.f, 0.f};
#pragma unroll 4
    for (int ks = 0; ks < 8; ++ks)
        kstep_pg<5, 8>(Apan, ks, Bk, 4096, ks * 32, wm * 64, lr, quad, acc);
    short* Cp = AM + (size_t)bc * 262144;
#pragma unroll
    for (int i = 0; i < 4; ++i)
#pragma unroll
        for (int j = 0; j < 8; ++j) {
            const int v = ft * 128 + wm * 64 + i * 16 + quad * 4;
            const int k = wn * 128 + j * 16 + lr;
#pragma unroll
            for (int r = 0; r < 4; ++r)
                Cp[(size_t)(v + r) * 512 + k] = f2bf(acc[i * 8 + j][r]);
        }
}

// ---------------- scan (blocks 0..255) + P = tril(Q K^T) (blocks 256..383) ----------------
__global__ __launch_bounds__(512, 2) void scan_phaseS(short* __restrict__ AM,
                                                      const short* __restrict__ Q,
                                                      const short* __restrict__ K,
                                                      short* __restrict__ P) {
    __shared__ __attribute__((aligned(16))) short Qpan[65536];
    if (blockIdx.x < 256) {
        int i = blockIdx.x * 512 + threadIdx.x;   // 0..131071
        int b = i >> 15;
        int vk8 = i & 32767;
        size_t base = (size_t)b * 16 * 262144 + (size_t)vk8 * 8;
        float acc[8];
#pragma unroll
        for (int s = 0; s < 8; ++s) acc[s] = 0.f;
        for (int c = 0; c < 16; ++c) {
            short* p = AM + base + (size_t)c * 262144;
            short in8[8];
            *(int4*)in8 = *(const int4*)p;
            short out8[8];
#pragma unroll
            for (int s = 0; s < 8; ++s) out8[s] = f2bf(acc[s]);
            *(int4*)p = *(const int4*)out8;
#pragma unroll
            for (int s = 0; s < 8; ++s) acc[s] += bf2f(in8[s]);
        }
        return;
    }
    const int e = blockIdx.x - 256;               // 0..127
    const int bc = e >> 1, mt = e & 1, b = bc >> 4, c = bc & 15;
    const int tid = threadIdx.x, lane = tid & 63, wv = tid >> 6;
    const int lr = lane & 15, quad = lane >> 4;
    const int wm = wv >> 2, wn = wv & 3;
    stage_panel<6>(Q + (size_t)(b * 4096 + c * 256 + mt * 128) * 512, 512, Qpan, tid);
    WAIT_BAR(0)
    const short* Bk = K + (size_t)(b * 4096 + c * 256 + wn * 64) * 512;
    f32x4 acc[16];
#pragma unroll
    for (int i = 0; i < 16; ++i) acc[i] = (f32x4){0.f, 0.f, 0.f, 0.f};
#pragma unroll 4
    for (int ks = 0; ks < 16; ++ks)
        kstep_pg<6, 4>(Qpan, ks, Bk, 512, ks * 32, wm * 64, lr, quad, acc);
    if (mt == 0 && wn >= 2) return;               // dead cols (never read by phaseY)
    short* Pt = P + (size_t)bc * 65536;
#pragma unroll
    for (int i = 0; i < 4; ++i)
#pragma unroll
        for (int j = 0; j < 4; ++j)
#pragma unroll
            for (int r = 0; r < 4; ++r) {
                const int trow = mt * 128 + wm * 64 + i * 16 + quad * 4 + r;
                const int jcol = wn * 64 + j * 16 + lr;
                Pt[(size_t)trow * 256 + jcol] = f2bf(jcol <= trow ? acc[i * 4 + j][r] : 0.f);
            }
}

// ---------------- phaseY: Y = Q Mpre^T + tril(P) V_c ; grid (2 mt, 2 nh, 64 bc) ----------------
__global__ __launch_bounds__(512, 2) void phaseY(const short* __restrict__ Q,
                                                 const short* __restrict__ Mpre,
                                                 const short* __restrict__ P,
                                                 const short* __restrict__ Vt,
                                                 short* __restrict__ Y) {
    __shared__ __attribute__((aligned(16))) short Ppan[32768];   // P, later Q half-1
    __shared__ __attribute__((aligned(16))) short Qpan[32768];   // Q half-0
    const int tid = threadIdx.x, lane = tid & 63, wv = tid >> 6;
    const int lr = lane & 15, quad = lane >> 4;
    const int wm = wv >> 2, wn = wv & 3;
    const int mt = blockIdx.x, nh = blockIdx.y, bc = blockIdx.z, b = bc >> 4, c = bc & 15;
    const short* Qrow = Q + (size_t)(b * 4096 + c * 256 + mt * 128) * 512;
    stage_panel<5>(P + (size_t)bc * 65536 + mt * 32768, 256, Ppan, tid);   // 8/thread
    __builtin_amdgcn_sched_barrier(0);
    stage_panel<5>(Qrow, 512, Qpan, tid);                                  // 8/thread
    WAIT_BAR(8)                                   // P landed everywhere; Q in flight
    f32x4 acc[16];
#pragma unroll
    for (int i = 0; i < 16; ++i) acc[i] = (f32x4){0.f, 0.f, 0.f, 0.f};
    // intra: A=P, B=Vt rows v; for mt=0 only j<128 valid
    const short* Bv = Vt + (size_t)(b * 512 + nh * 256 + wn * 64) * 4096 + c * 256;
#pragma unroll
    for (int ks = 0; ks < 4; ++ks)
        kstep_pg<5, 4>(Ppan, ks, Bv, 4096, ks * 32, wm * 64, lr, quad, acc);
    if (mt) {
#pragma unroll
        for (int ks = 4; ks < 8; ++ks)
            kstep_pg<5, 4>(Ppan, ks, Bv, 4096, ks * 32, wm * 64, lr, quad, acc);
    }
    WAIT_BAR(0)                                   // all Ppan reads done; Qh0 landed
    stage_panel<5>(Qrow + 256, 512, Ppan, tid);   // Q half-1 into Ppan
    __builtin_amdgcn_sched_barrier(0);
    // inter half-0 on Qpan while Qh1 flies
    const short* Bm = Mpre + (size_t)bc * 262144 + (size_t)(nh * 256 + wn * 64) * 512;
#pragma unroll 4
    for (int ks = 0; ks < 8; ++ks)
        kstep_pg<5, 4>(Qpan, ks, Bm, 512, ks * 32, wm * 64, lr, quad, acc);
    WAIT_BAR(0)                                   // Qh1 landed everywhere
#pragma unroll 4
    for (int ks = 0; ks < 8; ++ks)
        kstep_pg<5, 4>(Ppan, ks, Bm, 512, 256 + ks * 32, wm * 64, lr, quad, acc);
    short* Yt = Y + (size_t)(b * 4096 + c * 256 + mt * 128) * 512 + nh * 256;
#pragma unroll
    for (int i = 0; i < 4; ++i)
#pragma unroll
        for (int j = 0; j < 4; ++j)
#pragma unroll
            for (int r = 0; r < 4; ++r)
                Yt[(size_t)(wm * 64 + i * 16 + quad * 4 + r) * 512 + wn * 64 + j * 16 + lr] =
                    f2bf(acc[i * 4 + j][r]);
}

// ---------------- gemm_out: out[t][d] = sum_v Yb[t][v] WoT[d][v]; grid (4 dt, 64 tc) ----------------
__global__ __launch_bounds__(512, 2) void gemm_out(const short* __restrict__ Yb,
                                                   const short* __restrict__ WoT,
                                                   float* __restrict__ out) {
    __shared__ __attribute__((aligned(16))) short Wpan[65536];
    const int tid = threadIdx.x, lane = tid & 63, wv = tid >> 6;
    const int lr = lane & 15, quad = lane >> 4;
    const int wm = wv >> 2, wn = wv & 3;
    const int dt = blockIdx.x, tc = blockIdx.y;
    stage_panel<6>(WoT + (size_t)dt * 65536, 512, Wpan, tid);
    WAIT_BAR(0)
    const short* By = Yb + (size_t)(tc * 256 + wn * 64) * 512;
    f32x4 acc[16];
#pragma unroll
    for (int i = 0; i < 16; ++i) acc[i] = (f32x4){0.f, 0.f, 0.f, 0.f};
#pragma unroll 4
    for (int ks = 0; ks < 16; ++ks)
        kstep_pg<6, 4>(Wpan, ks, By, 512, ks * 32, wm * 64, lr, quad, acc);
    // C[m=d][n=t]: lane holds 4 consecutive d -> float4 store
#pragma unroll
    for (int i = 0; i < 4; ++i)
#pragma unroll
        for (int j = 0; j < 4; ++j) {
            const int d0 = dt * 128 + wm * 64 + i * 16 + quad * 4;
            const int t = tc * 256 + wn * 64 + j * 16 + lr;
            *(f32x4*)&out[(size_t)t * 512 + d0] = acc[i * 4 + j];
        }
}

// ---------------- host ----------------

extern "C" void kernel_launch(void* const* d_in, const int* in_sizes, int n_in,
                              void* d_out, int out_size, void* d_ws, size_t ws_size,
                              hipStream_t stream) {
    const float* x  = (const float*)d_in[0];
    const float* Wq = (const float*)d_in[1];
    const float* Wk = (const float*)d_in[2];
    const float* Wv = (const float*)d_in[3];
    const float* Wo = (const float*)d_in[4];
    float* out = (float*)d_out;

    const size_t NTD = 16384 * 512;   // 8,388,608 elems

    short* ws  = (short*)d_ws;
    short* Xp  = ws;                  // packed X fragments
    short* Qb  = Xp + NTD;
    short* Kb  = Qb + NTD;
    short* Kt  = Kb + NTD;
    short* Vt  = Kt + NTD;
    short* P   = Vt + NTD;            // 4.19M
    short* W4T = P + 4194304;         // 1.05M : PW (packed QKV) | WoT
    short* AM  = W4T + 1048576;       // 16.78M
    short* Yb  = Kb;                  // Kb dead after scan_phaseS

    short* PW  = W4T;
    short* WoT = W4T + 786432;

    prep_kernel<<<5504, 256, 0, stream>>>(x, Xp, Wq, Wk, Wv, Wo, PW, WoT);
    proj_qkv<<<256, 512, 0, stream>>>(Xp, PW, Qb, Kb, Vt, Kt);
    phaseA<<<dim3(4, 1, 64), 512, 0, stream>>>(Vt, Kt, AM);
    scan_phaseS<<<384, 512, 0, stream>>>(AM, Qb, Kb, P);
    phaseY<<<dim3(2, 2, 64), 512, 0, stream>>>(Qb, AM, P, Vt, Yb);
    gemm_out<<<dim3(4, 64), 512, 0, stream>>>(Yb, WoT, out);
}

// Round 8
// 229.880 us; speedup vs baseline: 1.0518x; 1.0518x over previous
//
#include <hip/hip_runtime.h>
#include <hip/hip_bf16.h>

typedef __attribute__((ext_vector_type(8))) short bf16x8;
typedef __attribute__((ext_vector_type(4))) float f32x4;

__device__ inline short f2bf(float f) {
    __hip_bfloat16 h = __float2bfloat16(f);
    short s;
    __builtin_memcpy(&s, &h, 2);
    return s;
}
__device__ inline float bf2f(short s) {
    unsigned int u = ((unsigned int)(unsigned short)s) << 16;
    float f;
    __builtin_memcpy(&f, &u, 4);
    return f;
}

// async 16B global->LDS; dest must be wave-uniform base + lane*16
__device__ inline void cp16_async(const void* g, void* l) {
    __builtin_amdgcn_global_load_lds(
        (const __attribute__((address_space(1))) void*)g,
        (__attribute__((address_space(3))) void*)l, 16, 0, 0);
}

// ---------------- prep (round-5, passing) ----------------

__global__ void prep_kernel(const float* __restrict__ x, short* __restrict__ Xp,
                            const float* __restrict__ W0, const float* __restrict__ W1,
                            const float* __restrict__ W2, const float* __restrict__ W3,
                            short* __restrict__ PW, short* __restrict__ WoT) {
    int bid = blockIdx.x;
    if (bid < 4096) {
        int f = bid * 256 + threadIdx.x;           // 0..1,048,575
        int mtf = f >> 13, r = f & 8191, kb = r >> 7, row = r & 127;
        const float* src = x + ((size_t)(mtf * 128 + row) * 512 + kb * 8);
        float4 a = ((const float4*)src)[0];
        float4 bq = ((const float4*)src)[1];
        short t[8];
        t[0] = f2bf(a.x);  t[1] = f2bf(a.y);  t[2] = f2bf(a.z);  t[3] = f2bf(a.w);
        t[4] = f2bf(bq.x); t[5] = f2bf(bq.y); t[6] = f2bf(bq.z); t[7] = f2bf(bq.w);
        ((int4*)Xp)[f] = *(const int4*)t;
    } else if (bid < 4480) {
        int g = (bid - 4096) * 256 + threadIdx.x;  // 0..98303
        int lane = g & 63, ksg = (g >> 6) & 15, nn = g >> 10;
        int w = nn >> 5;
        int nl = (nn & 31) * 16 + (lane & 15);
        int k0 = ksg * 32 + (lane >> 4) * 8;
        const float* W = (w == 0) ? W0 : (w == 1) ? W1 : W2;
        short t[8];
#pragma unroll
        for (int e = 0; e < 8; ++e) t[e] = f2bf(W[(size_t)(k0 + e) * 512 + nl]);
        ((int4*)PW)[g] = *(const int4*)t;
    } else {
        int i = (bid - 4480) * 256 + threadIdx.x;  // 0..262143
        int n = i >> 9, k = i & 511;
        WoT[i] = f2bf(W3[k * 512 + n]);
    }
}

// ---------------- proj_qkv (round-5 core; Kt epilogue -> packed PKt) ----------------
// PKt layout per (b,c) [131072 shorts]: frag(kg 0..31, ts 0..7) of 64 lanes x 16B;
// lane = ((t&31)>>3)*16 + (k&15); elem = t&7.   (B-frag-ready for phaseA)

#define KSTEP(ks) { \
    bf16x8 af[4], bfr[4]; \
    _Pragma("unroll") for (int i = 0; i < 4; ++i) \
        af[i] = *(const bf16x8*)&Xs[((ks) * 512 + quad * 128 + wm * 64 + i * 16 + lr) * 8]; \
    _Pragma("unroll") for (int j = 0; j < 4; ++j) \
        bfr[j] = *(const bf16x8*)&PB[((size_t)((j * 16 + (ks)) * 64 + lane)) * 8]; \
    _Pragma("unroll") for (int i = 0; i < 4; ++i) \
        _Pragma("unroll") for (int j = 0; j < 4; ++j) \
            acc[i * 4 + j] = __builtin_amdgcn_mfma_f32_16x16x32_bf16(af[i], bfr[j], acc[i * 4 + j], 0, 0, 0); }

__global__ __launch_bounds__(512, 2) void proj_qkv(const short* __restrict__ Xp,
                                                   const short* __restrict__ PW,
                                                   short* __restrict__ Qb, short* __restrict__ Kb,
                                                   short* __restrict__ Vt, short* __restrict__ PKt) {
    __shared__ __attribute__((aligned(16))) short Xs[65536];
    const int tid = threadIdx.x, lane = tid & 63, wv = tid >> 6;
    const int lr = lane & 15, quad = lane >> 4;
    const int wm = wv >> 2, wn = wv & 3;
    const int bid = blockIdx.x;
    const int swz = (bid & 7) * 32 + (bid >> 3);
    const int mt = swz >> 1, half = swz & 1;
    const short* Ap = Xp + (size_t)mt * 65536;
#pragma unroll
    for (int j = 0; j < 8; ++j) {
        const int f = j * 512 + tid;
        cp16_async(Ap + (size_t)f * 8, (char*)Xs + f * 16);
    }
    __builtin_amdgcn_sched_barrier(0);
#pragma unroll
    for (int j = 8; j < 16; ++j) {
        const int f = j * 512 + tid;
        cp16_async(Ap + (size_t)f * 8, (char*)Xs + f * 16);
    }
    __builtin_amdgcn_sched_barrier(0);
    const int b = mt >> 5;
    const int tl0 = (mt & 31) * 128 + wm * 64;
    const int trow0 = mt * 128 + wm * 64;
    for (int pass = 0; pass < 3; ++pass) {
        const int gc0 = half * 768 + pass * 256;
        f32x4 acc[16];
#pragma unroll
        for (int i = 0; i < 16; ++i) acc[i] = (f32x4){0.f, 0.f, 0.f, 0.f};
        const short* PB = PW + (size_t)((gc0 >> 4) + wn * 4) * 8192;
        if (pass == 0) {
            asm volatile("s_waitcnt vmcnt(8)" ::: "memory");
            __builtin_amdgcn_sched_barrier(0);
            __builtin_amdgcn_s_barrier();
            __builtin_amdgcn_sched_barrier(0);
#pragma unroll 4
            for (int ks = 0; ks < 8; ++ks) KSTEP(ks)
            __builtin_amdgcn_sched_barrier(0);
            asm volatile("s_waitcnt vmcnt(0)" ::: "memory");
            __builtin_amdgcn_sched_barrier(0);
            __builtin_amdgcn_s_barrier();
            __builtin_amdgcn_sched_barrier(0);
#pragma unroll 4
            for (int ks = 8; ks < 16; ++ks) KSTEP(ks)
        } else {
#pragma unroll 4
            for (int ks = 0; ks < 16; ++ks) KSTEP(ks)
        }
        const int p = gc0 >> 9;
        const int fc0 = (gc0 & 511) + wn * 64;
        if (p < 2) {                               // Q or K row-major [t][f]
            short* C = p ? Kb : Qb;
#pragma unroll
            for (int i = 0; i < 4; ++i)
#pragma unroll
                for (int j = 0; j < 4; ++j) {
                    const size_t base = (size_t)(trow0 + i * 16 + quad * 4) * 512 + fc0 + j * 16 + lr;
#pragma unroll
                    for (int r = 0; r < 4; ++r)
                        C[base + (size_t)r * 512] = f2bf(acc[i * 4 + j][r]);
                }
        }
        if (p == 1) {                              // packed Kt scatter (int2, same count as before)
#pragma unroll
            for (int i = 0; i < 4; ++i) {
                const int T0 = tl0 + i * 16 + quad * 4;     // t within batch
                const int c = T0 >> 8, tin = T0 & 255;
                const int ts = tin >> 5, tq = (tin & 31) >> 3, e0 = T0 & 7;  // e0 in {0,4}
#pragma unroll
                for (int j = 0; j < 4; ++j) {
                    const int f = fc0 + j * 16 + lr;        // k-feature
                    short tmp[4];
#pragma unroll
                    for (int r = 0; r < 4; ++r) tmp[r] = f2bf(acc[i * 4 + j][r]);
                    const size_t a = (size_t)(b * 16 + c) * 131072 +
                                     (size_t)(((f >> 4) * 8 + ts) * 64 + tq * 16 + (f & 15)) * 8 + e0;
                    *(int2*)&PKt[a] = *(const int2*)tmp;
                }
            }
        } else if (p == 2) {                       // Vt feature-major [b][f][t] (unchanged)
#pragma unroll
            for (int i = 0; i < 4; ++i)
#pragma unroll
                for (int j = 0; j < 4; ++j) {
                    const int f = fc0 + j * 16 + lr;
                    short tmp[4];
#pragma unroll
                    for (int r = 0; r < 4; ++r) tmp[r] = f2bf(acc[i * 4 + j][r]);
                    *(int2*)&Vt[((size_t)b * 512 + f) * 4096 + tl0 + i * 16 + quad * 4] = *(const int2*)tmp;
                }
        }
    }
}

// ========== persist-A pieces (round-6, correctness-proven) ==========

template <int SH>
__device__ inline void stage_panel(const short* __restrict__ G, int lda_s,
                                   short* lds, int tid) {
    constexpr int NF = 1 << SH;
#pragma unroll
    for (int j = 0; j < NF / 4; ++j) {
        const int s = j * 512 + tid;
        const int row = s >> SH;
        const int X = (s & (NF - 1)) ^ (row & 7);
        cp16_async(G + (size_t)row * lda_s + X * 8, (char*)lds + s * 16);
    }
}

// one K=32 step: A from persistent LDS panel, B streamed from PACKED global frags
template <int SH, int NJ, int NS>
__device__ inline void kstep_pb(const short* __restrict__ Apan, int ks,
                                const short* __restrict__ PB, int lane,
                                int mbase, int lr, int quad, f32x4* acc) {
    bf16x8 af[4], bfr[NJ];
#pragma unroll
    for (int i = 0; i < 4; ++i) {
        const int mr = mbase + i * 16 + lr;
        af[i] = *(const bf16x8*)&Apan[((mr << SH) + ((ks * 4 + quad) ^ (mr & 7))) * 8];
    }
#pragma unroll
    for (int j = 0; j < NJ; ++j)
        bfr[j] = *(const bf16x8*)&PB[((size_t)((j * NS + ks) * 64 + lane)) * 8];
#pragma unroll
    for (int i = 0; i < 4; ++i)
#pragma unroll
        for (int j = 0; j < NJ; ++j)
            acc[i * NJ + j] = __builtin_amdgcn_mfma_f32_16x16x32_bf16(af[i], bfr[j], acc[i * NJ + j], 0, 0, 0);
}

#define WAIT_BAR(N) \
    __builtin_amdgcn_sched_barrier(0); \
    asm volatile("s_waitcnt vmcnt(" #N ")" ::: "memory"); \
    __builtin_amdgcn_sched_barrier(0); \
    __builtin_amdgcn_s_barrier(); \
    __builtin_amdgcn_sched_barrier(0);

// ---------------- phaseA: AM[v][k] = sum_t Vt[v,t] Kt[k,t]; grid (4 ft, 2 kh, 64 bc) ----------------
__global__ __launch_bounds__(512, 2) void phaseA(const short* __restrict__ Vt,
                                                 const short* __restrict__ PKt,
                                                 short* __restrict__ AM) {
    __shared__ __attribute__((aligned(16))) short Apan[32768];   // 128 v-rows x 256 t
    const int tid = threadIdx.x, lane = tid & 63, wv = tid >> 6;
    const int lr = lane & 15, quad = lane >> 4;
    const int wm = wv >> 2, wn = wv & 3;
    const int ft = blockIdx.x, kh = blockIdx.y, bc = blockIdx.z, b = bc >> 4, c = bc & 15;
    stage_panel<5>(Vt + ((size_t)(b * 512 + ft * 128)) * 4096 + c * 256, 4096, Apan, tid);
    WAIT_BAR(0)
    const short* PB = PKt + (size_t)bc * 131072 + (size_t)(kh * 16 + wn * 4) * 4096;
    f32x4 acc[16];
#pragma unroll
    for (int i = 0; i < 16; ++i) acc[i] = (f32x4){0.f, 0.f, 0.f, 0.f};
#pragma unroll
    for (int ks = 0; ks < 8; ++ks)
        kstep_pb<5, 4, 8>(Apan, ks, PB, lane, wm * 64, lr, quad, acc);
    short* Cp = AM + (size_t)bc * 262144;
#pragma unroll
    for (int i = 0; i < 4; ++i)
#pragma unroll
        for (int j = 0; j < 4; ++j) {
            const int v = ft * 128 + wm * 64 + i * 16 + quad * 4;
            const int k = kh * 256 + wn * 64 + j * 16 + lr;
#pragma unroll
            for (int r = 0; r < 4; ++r)
                Cp[(size_t)(v + r) * 512 + k] = f2bf(acc[i * 4 + j][r]);
        }
}

// ========== 128x128 core, BK=32, 4-deep counted-vmcnt pipeline (rounds 4/5, passing) ==========

#define LDS_DECL __shared__ short sm[8][4096]

__device__ inline void stage32(const short* __restrict__ A, int lda,
                               const short* __restrict__ B, int ldb, int k0,
                               short* sA, short* sB, int tid) {
#pragma unroll
    for (int j = 0; j < 2; ++j) {
        const int L = tid * 16 + j * 4096;
        const int row = L >> 6;
        const int cb = (L & 63) ^ ((row & 3) << 4);
        cp16_async((const char*)(A + (size_t)row * lda + k0) + cb, (char*)sA + L);
        cp16_async((const char*)(B + (size_t)row * ldb + k0) + cb, (char*)sB + L);
    }
}

__device__ inline void compute32(const short* sA, const short* sB, f32x4* acc,
                                 int wr, int wc, int lr, int quad) {
    const int cb = (quad * 16) ^ ((lr & 3) << 4);
    bf16x8 af[4], bfr[4];
#pragma unroll
    for (int i = 0; i < 4; ++i)
        af[i] = *(const bf16x8*)((const char*)sA + (wr + i * 16 + lr) * 64 + cb);
#pragma unroll
    for (int j = 0; j < 4; ++j)
        bfr[j] = *(const bf16x8*)((const char*)sB + (wc + j * 16 + lr) * 64 + cb);
#pragma unroll
    for (int i = 0; i < 4; ++i)
#pragma unroll
        for (int j = 0; j < 4; ++j)
            acc[i * 4 + j] = __builtin_amdgcn_mfma_f32_16x16x32_bf16(af[i], bfr[j], acc[i * 4 + j], 0, 0, 0);
}

__device__ inline void kloop_pipe(const short* __restrict__ A, int lda,
                                  const short* __restrict__ B, int ldb, int Kd,
                                  f32x4* acc, short (*sm)[4096]) {
    const int tid = threadIdx.x, lane = tid & 63, wv = tid >> 6;
    const int quad = lane >> 4, lr = lane & 15;
    const int wr = (wv >> 1) * 64, wc = (wv & 1) * 64;
    const int NT = Kd >> 5;
    stage32(A, lda, B, ldb, 0,  sm[0], sm[1], tid);
    stage32(A, lda, B, ldb, 32, sm[2], sm[3], tid);
    stage32(A, lda, B, ldb, 64, sm[4], sm[5], tid);
    __builtin_amdgcn_sched_barrier(0);
    asm volatile("s_waitcnt vmcnt(8)" ::: "memory");
    __builtin_amdgcn_sched_barrier(0);
    __builtin_amdgcn_s_barrier();
    __builtin_amdgcn_sched_barrier(0);
    for (int t = 0; t < NT; ++t) {
        const int cur = (t & 3) << 1;
        if (t + 3 < NT)
            stage32(A, lda, B, ldb, (t + 3) << 5,
                    sm[((t + 3) & 3) << 1], sm[(((t + 3) & 3) << 1) + 1], tid);
        __builtin_amdgcn_sched_barrier(0);
        compute32(sm[cur], sm[cur + 1], acc, wr, wc, lr, quad);
        __builtin_amdgcn_sched_barrier(0);
        if (t + 3 < NT) {
            asm volatile("s_waitcnt vmcnt(8)" ::: "memory");
        } else if (t + 2 < NT) {
            asm volatile("s_waitcnt vmcnt(4)" ::: "memory");
        } else {
            asm volatile("s_waitcnt vmcnt(0)" ::: "memory");
        }
        __builtin_amdgcn_sched_barrier(0);
        __builtin_amdgcn_s_barrier();
        __builtin_amdgcn_sched_barrier(0);
    }
}

// ---------------- scan (0..511) + P = tril(Q K^T) (512..767); round-5, passing ----------------
__global__ __launch_bounds__(256, 2) void scan_phaseS(short* __restrict__ AM,
                                                      const short* __restrict__ Q,
                                                      const short* __restrict__ K,
                                                      short* __restrict__ P) {
    LDS_DECL;
    if (blockIdx.x < 512) {
        int i = blockIdx.x * 256 + threadIdx.x;
        int b = i >> 15;
        int vk8 = i & 32767;
        size_t base = (size_t)b * 16 * 262144 + (size_t)vk8 * 8;
        float acc[8];
#pragma unroll
        for (int s = 0; s < 8; ++s) acc[s] = 0.f;
        for (int c = 0; c < 16; ++c) {
            short* p = AM + base + (size_t)c * 262144;
            short in8[8];
            *(int4*)in8 = *(const int4*)p;
            short out8[8];
#pragma unroll
            for (int s = 0; s < 8; ++s) out8[s] = f2bf(acc[s]);
            *(int4*)p = *(const int4*)out8;
#pragma unroll
            for (int s = 0; s < 8; ++s) acc[s] += bf2f(in8[s]);
        }
        return;
    }
    const int e = blockIdx.x - 512;
    const int bc = e >> 2, mt = e & 1, nt = (e >> 1) & 1;
    if (mt < nt) return;
    const int b = bc >> 4, c = bc & 15;
    short* Pt = P + (size_t)bc * 65536 + (size_t)mt * 128 * 256 + nt * 128;
    const short* Ap = Q + ((size_t)(b * 4096 + c * 256 + mt * 128)) * 512;
    const short* Bp = K + ((size_t)(b * 4096 + c * 256 + nt * 128)) * 512;
    f32x4 acc[16];
#pragma unroll
    for (int i = 0; i < 16; ++i) acc[i] = (f32x4){0.f, 0.f, 0.f, 0.f};
    kloop_pipe(Ap, 512, Bp, 512, 512, acc, sm);
    const int lane = threadIdx.x & 63, wv = threadIdx.x >> 6;
    const int quad = lane >> 4, lr = lane & 15;
    const int wr = (wv >> 1) * 64, wc = (wv & 1) * 64;
    const bool diag = (mt == nt);
#pragma unroll
    for (int i = 0; i < 4; ++i)
#pragma unroll
        for (int j = 0; j < 4; ++j)
#pragma unroll
            for (int r = 0; r < 4; ++r) {
                int t = wr + i * 16 + quad * 4 + r;
                int jj = wc + j * 16 + lr;
                float v = (!diag || jj <= t) ? acc[i * 4 + j][r] : 0.f;
                Pt[(size_t)t * 256 + jj] = f2bf(v);
            }
}

// ---------------- phaseY (round-5 core; store -> packed PYb) ; grid (2 mt, 4 nt, 64 bc) ----------------
// PYb tile layout: frag index = tg*16 + (v>>5), tg = T>>4;
// lane = ((v&31)>>3)*16 + (T&15); elem = v&7.   (B-frag-ready for gemm_out)
__global__ __launch_bounds__(256, 2) void phaseY(const short* __restrict__ Q,
                                                 const short* __restrict__ Mpre,
                                                 const short* __restrict__ P,
                                                 const short* __restrict__ Vt,
                                                 short* __restrict__ PYb) {
    LDS_DECL;
    const int bc = blockIdx.z, b = bc >> 4, c = bc & 15;
    const int mt = blockIdx.x, nt = blockIdx.y;
    f32x4 acc[16];
#pragma unroll
    for (int i = 0; i < 16; ++i) acc[i] = (f32x4){0.f, 0.f, 0.f, 0.f};
    const short* Ai = Q + ((size_t)(b * 4096 + c * 256 + mt * 128)) * 512;
    const short* Bi = Mpre + (size_t)bc * 262144 + (size_t)nt * 128 * 512;
    kloop_pipe(Ai, 512, Bi, 512, 512, acc, sm);
    const short* Ap = P + (size_t)bc * 65536 + (size_t)mt * 128 * 256;
    const short* Bv = Vt + ((size_t)b * 512 + nt * 128) * 4096 + c * 256;
    kloop_pipe(Ap, 256, Bv, 4096, (mt + 1) * 128, acc, sm);
    const int lane = threadIdx.x & 63, wv = threadIdx.x >> 6;
    const int quad = lane >> 4, lr = lane & 15;
    const int wr = (wv >> 1) * 64, wc = (wv & 1) * 64;
    const int Tbase = b * 4096 + c * 256 + mt * 128 + wr;
#pragma unroll
    for (int i = 0; i < 4; ++i) {
        const int tg = (Tbase + i * 16) >> 4;
#pragma unroll
        for (int j = 0; j < 4; ++j) {
            const int v = nt * 128 + wc + j * 16 + lr;
            const size_t base = ((size_t)(tg * 16 + (v >> 5)) * 64 + ((v & 31) >> 3) * 16 + quad * 4) * 8 + (v & 7);
#pragma unroll
            for (int r = 0; r < 4; ++r)
                PYb[base + (size_t)r * 8] = f2bf(acc[i * 4 + j][r]);
        }
    }
}

// ---------------- gemm_out: out[t][d] = sum_v Yb[t][v] WoT[d][v]; grid (4 dt, 64 tc) ----------------
__global__ __launch_bounds__(512, 2) void gemm_out(const short* __restrict__ PYb,
                                                   const short* __restrict__ WoT,
                                                   float* __restrict__ out) {
    __shared__ __attribute__((aligned(16))) short Wpan[65536];
    const int tid = threadIdx.x, lane = tid & 63, wv = tid >> 6;
    const int lr = lane & 15, quad = lane >> 4;
    const int wm = wv >> 2, wn = wv & 3;
    const int dt = blockIdx.x, tc = blockIdx.y;
    stage_panel<6>(WoT + (size_t)dt * 65536, 512, Wpan, tid);
    WAIT_BAR(0)
    const short* PB = PYb + (size_t)(tc * 16 + wn * 4) * 8192;
    f32x4 acc[16];
#pragma unroll
    for (int i = 0; i < 16; ++i) acc[i] = (f32x4){0.f, 0.f, 0.f, 0.f};
#pragma unroll 4
    for (int ks = 0; ks < 16; ++ks)
        kstep_pb<6, 4, 16>(Wpan, ks, PB, lane, wm * 64, lr, quad, acc);
#pragma unroll
    for (int i = 0; i < 4; ++i)
#pragma unroll
        for (int j = 0; j < 4; ++j) {
            const int d0 = dt * 128 + wm * 64 + i * 16 + quad * 4;
            const int t = tc * 256 + wn * 64 + j * 16 + lr;
            *(f32x4*)&out[(size_t)t * 512 + d0] = acc[i * 4 + j];
        }
}

// ---------------- host ----------------

extern "C" void kernel_launch(void* const* d_in, const int* in_sizes, int n_in,
                              void* d_out, int out_size, void* d_ws, size_t ws_size,
                              hipStream_t stream) {
    const float* x  = (const float*)d_in[0];
    const float* Wq = (const float*)d_in[1];
    const float* Wk = (const float*)d_in[2];
    const float* Wv = (const float*)d_in[3];
    const float* Wo = (const float*)d_in[4];
    float* out = (float*)d_out;

    const size_t NTD = 16384 * 512;   // 8,388,608 elems

    short* ws  = (short*)d_ws;
    short* Xp  = ws;                  // packed X fragments
    short* Qb  = Xp + NTD;
    short* Kb  = Qb + NTD;
    short* PKt = Kb + NTD;            // packed Kt (old Kt slot)
    short* Vt  = PKt + NTD;
    short* P   = Vt + NTD;            // 4.19M
    short* W4T = P + 4194304;         // PW (packed QKV) | WoT
    short* AM  = W4T + 1048576;       // 16.78M
    short* PYb = Kb;                  // Kb dead after scan_phaseS

    short* PW  = W4T;
    short* WoT = W4T + 786432;

    prep_kernel<<<5504, 256, 0, stream>>>(x, Xp, Wq, Wk, Wv, Wo, PW, WoT);
    proj_qkv<<<256, 512, 0, stream>>>(Xp, PW, Qb, Kb, Vt, PKt);
    phaseA<<<dim3(4, 2, 64), 512, 0, stream>>>(Vt, PKt, AM);
    scan_phaseS<<<768, 256, 0, stream>>>(AM, Qb, Kb, P);
    phaseY<<<dim3(2, 4, 64), 256, 0, stream>>>(Qb, AM, P, Vt, PYb);
    gemm_out<<<dim3(4, 64), 512, 0, stream>>>(PYb, WoT, out);
}